// Round 14
// baseline (222.119 us; speedup 1.0000x reference)
//
#include <hip/hip_runtime.h>
#include <hip/hip_bf16.h>
#include <stdint.h>

typedef __attribute__((ext_vector_type(8))) short v8s;
typedef __attribute__((ext_vector_type(8))) __bf16 bf16x8;
typedef __attribute__((ext_vector_type(4))) float v4f;

__device__ __forceinline__ unsigned short f2bf(float f) {
  unsigned int u = __float_as_uint(f);
  u += 0x7fff + ((u >> 16) & 1);
  return (unsigned short)(u >> 16);
}
__device__ __forceinline__ float bf2f(unsigned short h) {
  return __uint_as_float(((unsigned int)h) << 16);
}

__device__ __forceinline__ void gload_lds16(const void* g, void* l) {
  __builtin_amdgcn_global_load_lds(
      (const __attribute__((address_space(1))) void*)g,
      (__attribute__((address_space(3))) void*)l,
      16, 0, 0);
}

// ---------------- merged cast f32 -> bf16 (x, wq, wk, wv, wo) ----------------
__global__ void cast_main(const float* __restrict__ x,  const float* __restrict__ wq,
                          const float* __restrict__ wk, const float* __restrict__ wv,
                          const float* __restrict__ wo,
                          unsigned short* __restrict__ xb, unsigned short* __restrict__ wqkvb,
                          unsigned short* __restrict__ wob) {
  const size_t MK = 8388608, NK = 4194304;  // 4096*2048, 2048*2048
  size_t i = ((size_t)blockIdx.x * 256 + threadIdx.x) * 4;
  const float* s; unsigned short* d; size_t off;
  if (i < MK)               { s = x;  d = xb;              off = i; }
  else if (i < MK + NK)     { s = wq; d = wqkvb;           off = i - MK; }
  else if (i < MK + 2 * NK) { s = wk; d = wqkvb + NK;      off = i - MK - NK; }
  else if (i < MK + 3 * NK) { s = wv; d = wqkvb + 2 * NK;  off = i - MK - 2 * NK; }
  else                      { s = wo; d = wob;             off = i - MK - 3 * NK; }
  float4 v = *(const float4*)(s + off);
  ushort4 o;
  o.x = f2bf(v.x); o.y = f2bf(v.y); o.z = f2bf(v.z); o.w = f2bf(v.w);
  *(ushort4*)(d + off) = o;
}

// ---------------- GEMM (m97 structure, 128x128, BK=64): C = A*B^T + bias ----
// Round-8 config (measured best). OUT=0: f32 row-major. OUT=1: fused QKV
// epilogue by column slice; ALL slices LDS-staged -> fully coalesced stores
// (kills partial-line write-allocate RMW traffic).
#define BM 128
#define BN 128
#define BK 64

template <int OUT>
__global__ __launch_bounds__(256, 2) void gemm_bt(
    const unsigned short* __restrict__ A,  // M x K bf16
    const unsigned short* __restrict__ B,  // Nfused x K bf16
    const float* __restrict__ bias0,
    const float* __restrict__ bias1,
    const float* __restrict__ bias2,
    void* __restrict__ D0, void* __restrict__ D1, void* __restrict__ D2,
    int K)
{
  __shared__ __align__(16) unsigned short Sh[2 * BM * BK];  // As | Bs, reused by epilogue
  unsigned short* As = Sh;
  unsigned short* Bs = Sh + BM * BK;

  const int tid  = threadIdx.x;
  const int lane = tid & 63;
  const int wid  = tid >> 6;            // 0..3
  const int wr   = wid >> 1, wc = wid & 1;

  const int tm = blockIdx.y * BM;
  const int tn = blockIdx.x * BN;

  const int srow = lane >> 3;
  const int scb  = lane & 7;
  const int gco  = (scb ^ srow) * 8;

  v4f acc[4][4];
#pragma unroll
  for (int m = 0; m < 4; ++m)
#pragma unroll
    for (int n = 0; n < 4; ++n)
      acc[m][n] = (v4f){0.f, 0.f, 0.f, 0.f};

  const unsigned short* Ab = A + (size_t)tm * K;
  const unsigned short* Bb = B + (size_t)tn * K;
  const int kTiles = K / BK;

  for (int kt = 0; kt < kTiles; ++kt) {
    const int k0 = kt * BK;
#pragma unroll
    for (int i = 0; i < 4; ++i) {
      const int r0 = wid * 32 + i * 8;
      gload_lds16(Ab + (size_t)(r0 + srow) * K + k0 + gco, &As[r0 * BK]);
    }
#pragma unroll
    for (int i = 0; i < 4; ++i) {
      const int r0 = wid * 32 + i * 8;
      gload_lds16(Bb + (size_t)(r0 + srow) * K + k0 + gco, &Bs[r0 * BK]);
    }
    __syncthreads();

#pragma unroll
    for (int ks = 0; ks < 2; ++ks) {
      bf16x8 av[4], bv[4];
#pragma unroll
      for (int m = 0; m < 4; ++m) {
        const int row  = wr * 64 + m * 16 + (lane & 15);
        const int cl   = ks * 4 + (lane >> 4);
        av[m] = *(const bf16x8*)&As[row * BK + ((cl ^ (row & 7)) * 8)];
      }
#pragma unroll
      for (int n = 0; n < 4; ++n) {
        const int row  = wc * 64 + n * 16 + (lane & 15);
        const int cl   = ks * 4 + (lane >> 4);
        bv[n] = *(const bf16x8*)&Bs[row * BK + ((cl ^ (row & 7)) * 8)];
      }
#pragma unroll
      for (int m = 0; m < 4; ++m)
#pragma unroll
        for (int n = 0; n < 4; ++n)
          acc[m][n] = __builtin_amdgcn_mfma_f32_16x16x32_bf16(av[m], bv[n], acc[m][n], 0, 0, 0);
    }
    __syncthreads();
  }

  const int cr0 = tm + wr * 64 + (lane >> 4) * 4;
  const int cc0 = tn + wc * 64 + (lane & 15);

  if (OUT == 0) {
    // f32 out: direct stores are 64B-aligned full segments (no RMW).
    float* Dp = (float*)D0;
#pragma unroll
    for (int n = 0; n < 4; ++n) {
      const int col = cc0 + n * 16;
      const float bz = bias0[col];
#pragma unroll
      for (int m = 0; m < 4; ++m) {
#pragma unroll
        for (int r = 0; r < 4; ++r) {
          const int rr = cr0 + m * 16 + r;
          Dp[(size_t)rr * 2048 + col] = acc[m][n][r] + bz;
        }
      }
    }
  } else {
    const int sid = tn >> 11;
    const float* bp = (sid == 0) ? bias0 : (sid == 1) ? bias1 : bias2;
    unsigned short* Dq = (unsigned short*)((sid == 0) ? D0 : (sid == 1) ? D1 : D2);

    // stage 128x128 tile (+bias) into LDS (32KB exactly)
    const int rl0 = wr * 64 + (lane >> 4) * 4;   // local row base
    const int clb = wc * 64 + (lane & 15);       // local col base
#pragma unroll
    for (int n = 0; n < 4; ++n) {
      const int cl = clb + n * 16;               // local col 0..127
      const float bz = bp[(tn & 2047) + cl];     // tn is multiple of 128
#pragma unroll
      for (int m = 0; m < 4; ++m) {
#pragma unroll
        for (int r = 0; r < 4; ++r) {
          Sh[(rl0 + m * 16 + r) * 128 + cl] = f2bf(acc[m][n][r] + bz);
        }
      }
    }
    __syncthreads();

    if (sid < 2) {
      // Q/K row-major: 256B contiguous per row, fully coalesced
      const int tn2 = tn & 2047;
#pragma unroll
      for (int it = 0; it < 8; ++it) {           // 8 * 256 * 8 = 16384 elems
        const int off = (it * 256 + tid) * 8;
        const int row = off >> 7, col = off & 127;
        *(v8s*)(Dq + (size_t)(tm + row) * 2048 + tn2 + col) = *(const v8s*)&Sh[off];
      }
    } else {
      // V transposed [b,h,l,d]: dest is one contiguous 32KB run
      const int bb = tm >> 11, ll0 = tm & 2047;
      const int hh = (tn & 2047) >> 7;
      unsigned short* dst = Dq + (((size_t)(bb * 16 + hh)) * 2048 + ll0) * 128;
#pragma unroll
      for (int it = 0; it < 8; ++it) {
        const int off = (it * 256 + tid) * 8;
        *(v8s*)(dst + off) = *(const v8s*)&Sh[off];
      }
    }
  }
}

// ---------------- RMSNorm (+ channel-shift mix for Q), writes transposed [b,h,l,d] ----------------
__global__ __launch_bounds__(256) void rmsnorm_mix(
    const unsigned short* __restrict__ Qb, const unsigned short* __restrict__ Kb,
    unsigned short* __restrict__ Qt, unsigned short* __restrict__ Kt,
    const float* __restrict__ gq, const float* __restrict__ gk,
    const float* __restrict__ wmix)
{
  const int row = blockIdx.x;            // b*L + l
  const bool isQ = (blockIdx.y == 0);
  const unsigned short* src = (isQ ? Qb : Kb) + (size_t)row * 2048;
  unsigned short* dstbase = isQ ? Qt : Kt;
  const float* g = isQ ? gq : gk;
  const int b = row >> 11, l = row & 2047;

  __shared__ float sv[2048];
  __shared__ float red[4];

  const int t = threadIdx.x;
  v8s raw = *(const v8s*)(src + t * 8);
  float x[8];
  float ss = 0.f;
#pragma unroll
  for (int j = 0; j < 8; ++j) { x[j] = bf2f((unsigned short)raw[j]); ss += x[j] * x[j]; }
#pragma unroll
  for (int o = 32; o > 0; o >>= 1) ss += __shfl_xor(ss, o, 64);
  if ((t & 63) == 0) red[t >> 6] = ss;
  __syncthreads();
  const float tot = red[0] + red[1] + red[2] + red[3];
  const float inv = rsqrtf(tot * (1.0f / 2048.0f) + 1e-6f);

  const int h = t >> 4;
  unsigned short* dst = dstbase + (((size_t)(b * 16 + h)) * 2048 + l) * 128 + ((t * 8) & 127);

  if (isQ) {
#pragma unroll
    for (int j = 0; j < 8; ++j) sv[t * 8 + j] = x[j] * inv * g[t * 8 + j];
    __syncthreads();
    const float scale = 0.08838834764831845f;  // 1/sqrt(128)
    const float w0 = wmix[0], w1 = wmix[1], w2 = wmix[2], w3 = wmix[3], w4 = wmix[4];
    v8s ov;
#pragma unroll
    for (int j = 0; j < 8; ++j) {
      const int idx = t * 8 + j;
      const int hb = idx & ~127;
      const int d  = idx & 127;
      float a = w0 * sv[hb + d]
              + w1 * sv[hb + ((d - 1) & 127)]
              + w2 * sv[hb + ((d - 2) & 127)]
              + w3 * sv[hb + ((d - 4) & 127)]
              + w4 * sv[hb + ((d - 8) & 127)];
      ov[j] = (short)f2bf(a * scale);
    }
    *(v8s*)dst = ov;
  } else {
    v8s ov;
#pragma unroll
    for (int j = 0; j < 8; ++j) ov[j] = (short)f2bf(x[j] * inv * g[t * 8 + j]);
    *(v8s*)dst = ov;
  }
}

// ---------------- attention: LDS-staged small shifts + global large shifts ---
// Round-8 verbatim (measured ~31us): dual K/V buffers, launch_bounds(512,1).
__global__ __launch_bounds__(512, 1) void attention_k(
    const unsigned short* __restrict__ Qt,
    const unsigned short* __restrict__ Kt,
    const unsigned short* __restrict__ Vt,
    unsigned short* __restrict__ AO)
{
  const int bid   = blockIdx.x;          // ch*32 + plane
  const int plane = bid & 31;
  const int ch    = bid >> 5;            // 0..15
  const int b = plane >> 4, h = plane & 15;
  const int l0 = ch * 128;
  const int w0 = (l0 + 2048 - 64) & 2047;   // staged window start

  __shared__ __align__(16) unsigned short Ks[256 * 128];  // 64KB
  __shared__ __align__(16) unsigned short Vs[256 * 128];  // 64KB
  __shared__ float sc[128][17];

  const int t    = threadIdx.x;
  const int lane = t & 63;
  const int w    = t >> 6;               // wave 0..7
  const int li   = t >> 2;               // 0..127
  const int q    = t & 3;                // 32-elem d quarter
  const int myl  = l0 + li;

  const size_t pbase = (size_t)plane * (2048 * 128);

  // ---- stage 256-row K and V windows ----
  {
    const int lr4 = lane >> 4;           // row within 4-row segment
    const int cp  = lane & 15;           // phys chunk this lane fills
#pragma unroll
    for (int j = 0; j < 8; ++j) {
      const int seg = w * 8 + j;         // 0..63
      const int rl  = seg * 4 + lr4;     // local row 0..255
      const int cl  = cp ^ (rl & 7);     // logical chunk to fetch
      const int g   = (w0 + rl) & 2047;
      gload_lds16(Kt + pbase + (size_t)g * 128 + cl * 8, &Ks[seg * 512]);
      gload_lds16(Vt + pbase + (size_t)g * 128 + cl * 8, &Vs[seg * 512]);
    }
  }

  // Q slice -> f32 (overlaps staging latency)
  float qf[32];
  {
    const unsigned short* qp = Qt + pbase + (size_t)myl * 128 + q * 32;
#pragma unroll
    for (int i = 0; i < 4; ++i) {
      v8s qv = *(const v8s*)(qp + i * 8);
#pragma unroll
      for (int j = 0; j < 8; ++j) qf[i * 8 + j] = bf2f((unsigned short)qv[j]);
    }
  }

  asm volatile("s_waitcnt vmcnt(0)" ::: "memory");
  __syncthreads();

  const int SH[16] = {0, 1, -1, 3, -3, 7, -7, 20, -20, 53, -53, 141, -141, 380, -380, 1024};

  // pass 1: scores
#pragma unroll
  for (int s = 0; s < 16; ++s) {
    float dot = 0.f;
    if (s < 11) {
      const int rl = li + 64 - SH[s];    // in [11, 244]
#pragma unroll
      for (int i = 0; i < 4; ++i) {
        v8s kv = *(const v8s*)&Ks[rl * 128 + (((q * 4 + i) ^ (rl & 7)) * 8)];
#pragma unroll
        for (int j = 0; j < 8; ++j) dot += qf[i * 8 + j] * bf2f((unsigned short)kv[j]);
      }
    } else {
      const int row = (myl - SH[s]) & 2047;
      const unsigned short* kp = Kt + pbase + (size_t)row * 128 + q * 32;
#pragma unroll
      for (int i = 0; i < 4; ++i) {
        v8s kv = *(const v8s*)(kp + i * 8);
#pragma unroll
        for (int j = 0; j < 8; ++j) dot += qf[i * 8 + j] * bf2f((unsigned short)kv[j]);
      }
    }
    dot += __shfl_xor(dot, 1, 64);
    dot += __shfl_xor(dot, 2, 64);
    if (q == 0) sc[li][s] = dot;
  }
  __syncthreads();

  // softmax over 16 shifts
  {
    float v0[16];
#pragma unroll
    for (int s = 0; s < 16; ++s) v0[s] = sc[li][s];
    float mx = v0[0];
#pragma unroll
    for (int s = 1; s < 16; ++s) mx = fmaxf(mx, v0[s]);
    float sum = 0.f;
    float e[4];
#pragma unroll
    for (int s = 0; s < 16; ++s) {
      const float ee = __expf(v0[s] - mx);
      sum += ee;
      if ((s >> 2) == q) e[s & 3] = ee;
    }
    const float inv = 1.f / sum;
    __syncthreads();
#pragma unroll
    for (int i = 0; i < 4; ++i) sc[li][q * 4 + i] = e[i] * inv;
  }
  __syncthreads();

  // pass 2: output accumulate
  float o[32];
#pragma unroll
  for (int i = 0; i < 32; ++i) o[i] = 0.f;
#pragma unroll
  for (int s = 0; s < 16; ++s) {
    const float p = sc[li][s];
    if (s < 11) {
      const int rl = li + 64 - SH[s];
#pragma unroll
      for (int i = 0; i < 4; ++i) {
        v8s vv = *(const v8s*)&Vs[rl * 128 + (((q * 4 + i) ^ (rl & 7)) * 8)];
#pragma unroll
        for (int j = 0; j < 8; ++j) o[i * 8 + j] += p * bf2f((unsigned short)vv[j]);
      }
    } else {
      const int row = (myl - SH[s]) & 2047;
      const unsigned short* vp = Vt + pbase + (size_t)row * 128 + q * 32;
#pragma unroll
      for (int i = 0; i < 4; ++i) {
        v8s vv = *(const v8s*)(vp + i * 8);
#pragma unroll
        for (int j = 0; j < 8; ++j) o[i * 8 + j] += p * bf2f((unsigned short)vv[j]);
      }
    }
  }

  unsigned short* op = AO + ((size_t)(b * 2048 + myl)) * 2048 + h * 128 + q * 32;
#pragma unroll
  for (int i = 0; i < 4; ++i) {
    v8s ov;
#pragma unroll
    for (int j = 0; j < 8; ++j) ov[j] = (short)f2bf(o[i * 8 + j]);
    *(v8s*)(op + i * 8) = ov;
  }
}

// ---------------- launch ----------------
extern "C" void kernel_launch(void* const* d_in, const int* in_sizes, int n_in,
                              void* d_out, int out_size, void* d_ws, size_t ws_size,
                              hipStream_t stream) {
  const float* x    = (const float*)d_in[0];
  const float* wq   = (const float*)d_in[1];
  const float* bq   = (const float*)d_in[2];
  const float* wk   = (const float*)d_in[3];
  const float* bk   = (const float*)d_in[4];
  const float* wv   = (const float*)d_in[5];
  const float* bv   = (const float*)d_in[6];
  const float* gq   = (const float*)d_in[7];
  const float* gk   = (const float*)d_in[8];
  const float* wmix = (const float*)d_in[9];
  const float* wo   = (const float*)d_in[10];
  const float* bo   = (const float*)d_in[11];

  const int M = 4096;      // B*L
  const int K = 2048;      // QUERY_DIM
  const size_t MB = 1024 * 1024;

  char* ws = (char*)d_ws;
  // workspace (112 MB):
  unsigned short* xb    = (unsigned short*)(ws + 0 * MB);    // 16MB; dead after QKV gemm
  unsigned short* Ktr   = (unsigned short*)(ws + 0 * MB);    // alias xb
  unsigned short* wqkvb = (unsigned short*)(ws + 16 * MB);   // 24MB
  unsigned short* Qb    = (unsigned short*)(ws + 40 * MB);   // 16MB; dead after rmsnorm
  unsigned short* AOb   = (unsigned short*)(ws + 40 * MB);   // alias Qb
  unsigned short* Kb    = (unsigned short*)(ws + 56 * MB);   // 16MB
  unsigned short* Vt    = (unsigned short*)(ws + 72 * MB);   // 16MB (transposed V)
  unsigned short* Qtr   = (unsigned short*)(ws + 88 * MB);   // 16MB
  unsigned short* wob   = (unsigned short*)(ws + 104 * MB);  // 8MB

  // all five casts in one kernel (25.2M elems, 4/thread)
  cast_main<<<24576, 256, 0, stream>>>(x, wq, wk, wv, wo, xb, wqkvb, wob);

  // fused QKV GEMM: 128x128 tiles, grid 48 x 32 (round-8 measured-best)
  gemm_bt<1><<<dim3(48, 32), 256, 0, stream>>>(xb, wqkvb, bq, bk, bv, Qb, Kb, Vt, K);

  rmsnorm_mix<<<dim3(M, 2), 256, 0, stream>>>(Qb, Kb, Qtr, Ktr, gq, gk, wmix);
  attention_k<<<512, 512, 0, stream>>>(Qtr, Ktr, Vt, AOb);

  // out-proj: 128x128 tiles, grid 16 x 32
  gemm_bt<0><<<dim3(16, 32), 256, 0, stream>>>(AOb, wob, bo, nullptr, nullptr, d_out, nullptr, nullptr, K);
}

// Round 15
// 215.580 us; speedup vs baseline: 1.0303x; 1.0303x over previous
//
#include <hip/hip_runtime.h>
#include <hip/hip_bf16.h>
#include <stdint.h>

typedef __attribute__((ext_vector_type(8))) short v8s;
typedef __attribute__((ext_vector_type(8))) __bf16 bf16x8;
typedef __attribute__((ext_vector_type(4))) float v4f;

__device__ __forceinline__ unsigned short f2bf(float f) {
  unsigned int u = __float_as_uint(f);
  u += 0x7fff + ((u >> 16) & 1);
  return (unsigned short)(u >> 16);
}
__device__ __forceinline__ float bf2f(unsigned short h) {
  return __uint_as_float(((unsigned int)h) << 16);
}

__device__ __forceinline__ void gload_lds16(const void* g, void* l) {
  __builtin_amdgcn_global_load_lds(
      (const __attribute__((address_space(1))) void*)g,
      (__attribute__((address_space(3))) void*)l,
      16, 0, 0);
}

// ---------------- merged cast f32 -> bf16 (x, wq, wk, wv, wo) ----------------
__global__ void cast_main(const float* __restrict__ x,  const float* __restrict__ wq,
                          const float* __restrict__ wk, const float* __restrict__ wv,
                          const float* __restrict__ wo,
                          unsigned short* __restrict__ xb, unsigned short* __restrict__ wqkvb,
                          unsigned short* __restrict__ wob) {
  const size_t MK = 8388608, NK = 4194304;  // 4096*2048, 2048*2048
  size_t i = ((size_t)blockIdx.x * 256 + threadIdx.x) * 4;
  const float* s; unsigned short* d; size_t off;
  if (i < MK)               { s = x;  d = xb;              off = i; }
  else if (i < MK + NK)     { s = wq; d = wqkvb;           off = i - MK; }
  else if (i < MK + 2 * NK) { s = wk; d = wqkvb + NK;      off = i - MK - NK; }
  else if (i < MK + 3 * NK) { s = wv; d = wqkvb + 2 * NK;  off = i - MK - 2 * NK; }
  else                      { s = wo; d = wob;             off = i - MK - 3 * NK; }
  float4 v = *(const float4*)(s + off);
  ushort4 o;
  o.x = f2bf(v.x); o.y = f2bf(v.y); o.z = f2bf(v.z); o.w = f2bf(v.w);
  *(ushort4*)(d + off) = o;
}

// ---------------- GEMM (m97 structure, 128x128, BK=64): C = A*B^T + bias ----
#define BM 128
#define BN 128
#define BK 64

template <int OUT>
__global__ __launch_bounds__(256, 2) void gemm_bt(
    const unsigned short* __restrict__ A,  // M x K bf16
    const unsigned short* __restrict__ B,  // Nfused x K bf16
    const float* __restrict__ bias0,
    const float* __restrict__ bias1,
    const float* __restrict__ bias2,
    void* __restrict__ D0, void* __restrict__ D1, void* __restrict__ D2,
    int K)
{
  __shared__ __align__(16) unsigned short Sh[2 * BM * BK];  // As | Bs, reused by epilogue
  unsigned short* As = Sh;
  unsigned short* Bs = Sh + BM * BK;

  const int tid  = threadIdx.x;
  const int lane = tid & 63;
  const int wid  = tid >> 6;            // 0..3
  const int wr   = wid >> 1, wc = wid & 1;

  const int tm = blockIdx.y * BM;
  const int tn = blockIdx.x * BN;

  const int srow = lane >> 3;
  const int scb  = lane & 7;
  const int gco  = (scb ^ srow) * 8;

  v4f acc[4][4];
#pragma unroll
  for (int m = 0; m < 4; ++m)
#pragma unroll
    for (int n = 0; n < 4; ++n)
      acc[m][n] = (v4f){0.f, 0.f, 0.f, 0.f};

  const unsigned short* Ab = A + (size_t)tm * K;
  const unsigned short* Bb = B + (size_t)tn * K;
  const int kTiles = K / BK;

  for (int kt = 0; kt < kTiles; ++kt) {
    const int k0 = kt * BK;
#pragma unroll
    for (int i = 0; i < 4; ++i) {
      const int r0 = wid * 32 + i * 8;
      gload_lds16(Ab + (size_t)(r0 + srow) * K + k0 + gco, &As[r0 * BK]);
    }
#pragma unroll
    for (int i = 0; i < 4; ++i) {
      const int r0 = wid * 32 + i * 8;
      gload_lds16(Bb + (size_t)(r0 + srow) * K + k0 + gco, &Bs[r0 * BK]);
    }
    __syncthreads();

#pragma unroll
    for (int ks = 0; ks < 2; ++ks) {
      bf16x8 av[4], bv[4];
#pragma unroll
      for (int m = 0; m < 4; ++m) {
        const int row  = wr * 64 + m * 16 + (lane & 15);
        const int cl   = ks * 4 + (lane >> 4);
        av[m] = *(const bf16x8*)&As[row * BK + ((cl ^ (row & 7)) * 8)];
      }
#pragma unroll
      for (int n = 0; n < 4; ++n) {
        const int row  = wc * 64 + n * 16 + (lane & 15);
        const int cl   = ks * 4 + (lane >> 4);
        bv[n] = *(const bf16x8*)&Bs[row * BK + ((cl ^ (row & 7)) * 8)];
      }
#pragma unroll
      for (int m = 0; m < 4; ++m)
#pragma unroll
        for (int n = 0; n < 4; ++n)
          acc[m][n] = __builtin_amdgcn_mfma_f32_16x16x32_bf16(av[m], bv[n], acc[m][n], 0, 0, 0);
    }
    __syncthreads();
  }

  const int cr0 = tm + wr * 64 + (lane >> 4) * 4;
  const int cc0 = tn + wc * 64 + (lane & 15);

  if (OUT == 0) {
    float* Dp = (float*)D0;
#pragma unroll
    for (int n = 0; n < 4; ++n) {
      const int col = cc0 + n * 16;
      const float bz = bias0[col];
#pragma unroll
      for (int m = 0; m < 4; ++m) {
#pragma unroll
        for (int r = 0; r < 4; ++r) {
          const int rr = cr0 + m * 16 + r;
          Dp[(size_t)rr * 2048 + col] = acc[m][n][r] + bz;
        }
      }
    }
  } else {
    const int sid = tn >> 11;
    const float* bp = (sid == 0) ? bias0 : (sid == 1) ? bias1 : bias2;
    unsigned short* Dq = (unsigned short*)((sid == 0) ? D0 : (sid == 1) ? D1 : D2);

    // stage 128x128 tile (+bias) into LDS (32KB exactly)
    const int rl0 = wr * 64 + (lane >> 4) * 4;   // local row base
    const int clb = wc * 64 + (lane & 15);       // local col base
#pragma unroll
    for (int n = 0; n < 4; ++n) {
      const int cl = clb + n * 16;               // local col 0..127
      const float bz = bp[(tn & 2047) + cl];     // tn is multiple of 128
#pragma unroll
      for (int m = 0; m < 4; ++m) {
#pragma unroll
        for (int r = 0; r < 4; ++r) {
          Sh[(rl0 + m * 16 + r) * 128 + cl] = f2bf(acc[m][n][r] + bz);
        }
      }
    }
    __syncthreads();

    if (sid < 2) {
      const int tn2 = tn & 2047;
#pragma unroll
      for (int it = 0; it < 8; ++it) {           // 8 * 256 * 8 = 16384 elems
        const int off = (it * 256 + tid) * 8;
        const int row = off >> 7, col = off & 127;
        *(v8s*)(Dq + (size_t)(tm + row) * 2048 + tn2 + col) = *(const v8s*)&Sh[off];
      }
    } else {
      const int bb = tm >> 11, ll0 = tm & 2047;
      const int hh = (tn & 2047) >> 7;
      unsigned short* dst = Dq + (((size_t)(bb * 16 + hh)) * 2048 + ll0) * 128;
#pragma unroll
      for (int it = 0; it < 8; ++it) {
        const int off = (it * 256 + tid) * 8;
        *(v8s*)(dst + off) = *(const v8s*)&Sh[off];
      }
    }
  }
}

// ---------------- per-row inverse RMS norms for Q and K ----------------------
__global__ __launch_bounds__(256) void row_norms(
    const unsigned short* __restrict__ Qb, const unsigned short* __restrict__ Kb,
    float* __restrict__ invQ, float* __restrict__ invK)
{
  const int row = blockIdx.x;            // 0..4095 (b*L + l)
  const bool isQ = (blockIdx.y == 0);
  const unsigned short* src = (isQ ? Qb : Kb) + (size_t)row * 2048;
  __shared__ float red[4];

  const int t = threadIdx.x;
  v8s raw = *(const v8s*)(src + t * 8);
  float ss = 0.f;
#pragma unroll
  for (int j = 0; j < 8; ++j) { float x = bf2f((unsigned short)raw[j]); ss += x * x; }
#pragma unroll
  for (int o = 32; o > 0; o >>= 1) ss += __shfl_xor(ss, o, 64);
  if ((t & 63) == 0) red[t >> 6] = ss;
  __syncthreads();
  if (t == 0) {
    const float tot = red[0] + red[1] + red[2] + red[3];
    (isQ ? invQ : invK)[row] = rsqrtf(tot * (1.0f / 2048.0f) + 1e-6f);
  }
}

// ---------------- attention: norm-folded, LDS-staged small shifts ------------
// Q: raw Qb row -> in-register rmsnorm+gain+mix (shfl for cross-thread shifts),
// gk folded into q-side. K staged raw from row-major Kb; score *= invK[row].
__global__ __launch_bounds__(512, 1) void attention_k(
    const unsigned short* __restrict__ Qb,
    const unsigned short* __restrict__ Kb,
    const unsigned short* __restrict__ Vt,
    const float* __restrict__ invQ, const float* __restrict__ invK,
    const float* __restrict__ gq, const float* __restrict__ gk,
    const float* __restrict__ wmix,
    unsigned short* __restrict__ AO)
{
  const int bid   = blockIdx.x;          // ch*32 + plane
  const int plane = bid & 31;
  const int ch    = bid >> 5;            // 0..15
  const int b = plane >> 4, h = plane & 15;
  const int l0 = ch * 128;
  const int w0 = (l0 + 2048 - 64) & 2047;   // staged window start

  __shared__ __align__(16) unsigned short Ks[256 * 128];  // 64KB (raw K)
  __shared__ __align__(16) unsigned short Vs[256 * 128];  // 64KB
  __shared__ float sc[128][17];

  const int t    = threadIdx.x;
  const int lane = t & 63;
  const int w    = t >> 6;               // wave 0..7
  const int li   = t >> 2;               // 0..127
  const int q    = t & 3;                // 32-elem d quarter
  const int myl  = l0 + li;
  const int grow = b * 2048 + myl;

  const size_t pbase = (size_t)plane * (2048 * 128);

  // ---- stage 256-row K (from row-major Kb) and V windows ----
  {
    const int lr4 = lane >> 4;           // row within 4-row segment
    const int cp  = lane & 15;           // phys chunk this lane fills
#pragma unroll
    for (int j = 0; j < 8; ++j) {
      const int seg = w * 8 + j;         // 0..63
      const int rl  = seg * 4 + lr4;     // local row 0..255
      const int cl  = cp ^ (rl & 7);     // logical chunk to fetch
      const int g   = (w0 + rl) & 2047;
      gload_lds16(Kb + ((size_t)(b * 2048 + g)) * 2048 + h * 128 + cl * 8, &Ks[seg * 512]);
      gload_lds16(Vt + pbase + (size_t)g * 128 + cl * 8, &Vs[seg * 512]);
    }
  }

  // ---- Q: load raw, normalize, mix, fold gk (overlaps staging latency) ----
  float qg[32];
  {
    float qn[32];
    const unsigned short* qp = Qb + (size_t)grow * 2048 + h * 128 + q * 32;
    const float iq = invQ[grow];
    const float* gqp = gq + h * 128 + q * 32;
#pragma unroll
    for (int i = 0; i < 4; ++i) {
      v8s qv = *(const v8s*)(qp + i * 8);
#pragma unroll
      for (int j = 0; j < 8; ++j)
        qn[i * 8 + j] = bf2f((unsigned short)qv[j]) * iq * gqp[i * 8 + j];
    }
    // neighbor's top 8 (circular within the 128-dim head): lane of quarter q-1
    float prev[8];
    const int nb = (t & ~3) | ((q + 3) & 3);
#pragma unroll
    for (int j = 0; j < 8; ++j) prev[j] = __shfl(qn[24 + j], nb & 63, 64);
    const float scale = 0.08838834764831845f;  // 1/sqrt(128)
    const float w0m = wmix[0] * scale, w1m = wmix[1] * scale, w2m = wmix[2] * scale;
    const float w3m = wmix[3] * scale, w4m = wmix[4] * scale;
    const float* gkp = gk + h * 128 + q * 32;
#pragma unroll
    for (int i = 0; i < 32; ++i) {
      const float s1 = (i >= 1) ? qn[i - 1] : prev[7 + i];      // prev[8+i-1]
      const float s2 = (i >= 2) ? qn[i - 2] : prev[6 + i];
      const float s4 = (i >= 4) ? qn[i - 4] : prev[4 + i];
      const float s8 = (i >= 8) ? qn[i - 8] : prev[i];
      qg[i] = (w0m * qn[i] + w1m * s1 + w2m * s2 + w3m * s4 + w4m * s8) * gkp[i];
    }
  }

  asm volatile("s_waitcnt vmcnt(0)" ::: "memory");
  __syncthreads();

  const int SH[16] = {0, 1, -1, 3, -3, 7, -7, 20, -20, 53, -53, 141, -141, 380, -380, 1024};

  // pass 1: scores (score = (qg . k_raw) * invK[row])
#pragma unroll
  for (int s = 0; s < 16; ++s) {
    const int row = (myl - SH[s]) & 2047;
    float dot = 0.f;
    if (s < 11) {
      const int rl = li + 64 - SH[s];    // in [11, 244]
#pragma unroll
      for (int i = 0; i < 4; ++i) {
        v8s kv = *(const v8s*)&Ks[rl * 128 + (((q * 4 + i) ^ (rl & 7)) * 8)];
#pragma unroll
        for (int j = 0; j < 8; ++j) dot += qg[i * 8 + j] * bf2f((unsigned short)kv[j]);
      }
    } else {
      const unsigned short* kp = Kb + ((size_t)(b * 2048 + row)) * 2048 + h * 128 + q * 32;
#pragma unroll
      for (int i = 0; i < 4; ++i) {
        v8s kv = *(const v8s*)(kp + i * 8);
#pragma unroll
        for (int j = 0; j < 8; ++j) dot += qg[i * 8 + j] * bf2f((unsigned short)kv[j]);
      }
    }
    dot += __shfl_xor(dot, 1, 64);
    dot += __shfl_xor(dot, 2, 64);
    if (q == 0) sc[li][s] = dot * invK[b * 2048 + row];
  }
  __syncthreads();

  // softmax over 16 shifts
  {
    float v0[16];
#pragma unroll
    for (int s = 0; s < 16; ++s) v0[s] = sc[li][s];
    float mx = v0[0];
#pragma unroll
    for (int s = 1; s < 16; ++s) mx = fmaxf(mx, v0[s]);
    float sum = 0.f;
    float e[4];
#pragma unroll
    for (int s = 0; s < 16; ++s) {
      const float ee = __expf(v0[s] - mx);
      sum += ee;
      if ((s >> 2) == q) e[s & 3] = ee;
    }
    const float inv = 1.f / sum;
    __syncthreads();
#pragma unroll
    for (int i = 0; i < 4; ++i) sc[li][q * 4 + i] = e[i] * inv;
  }
  __syncthreads();

  // pass 2: output accumulate
  float o[32];
#pragma unroll
  for (int i = 0; i < 32; ++i) o[i] = 0.f;
#pragma unroll
  for (int s = 0; s < 16; ++s) {
    const float p = sc[li][s];
    if (s < 11) {
      const int rl = li + 64 - SH[s];
#pragma unroll
      for (int i = 0; i < 4; ++i) {
        v8s vv = *(const v8s*)&Vs[rl * 128 + (((q * 4 + i) ^ (rl & 7)) * 8)];
#pragma unroll
        for (int j = 0; j < 8; ++j) o[i * 8 + j] += p * bf2f((unsigned short)vv[j]);
      }
    } else {
      const int row = (myl - SH[s]) & 2047;
      const unsigned short* vp = Vt + pbase + (size_t)row * 128 + q * 32;
#pragma unroll
      for (int i = 0; i < 4; ++i) {
        v8s vv = *(const v8s*)(vp + i * 8);
#pragma unroll
        for (int j = 0; j < 8; ++j) o[i * 8 + j] += p * bf2f((unsigned short)vv[j]);
      }
    }
  }

  unsigned short* op = AO + ((size_t)grow) * 2048 + h * 128 + q * 32;
#pragma unroll
  for (int i = 0; i < 4; ++i) {
    v8s ov;
#pragma unroll
    for (int j = 0; j < 8; ++j) ov[j] = (short)f2bf(o[i * 8 + j]);
    *(v8s*)(op + i * 8) = ov;
  }
}

// ---------------- launch ----------------
extern "C" void kernel_launch(void* const* d_in, const int* in_sizes, int n_in,
                              void* d_out, int out_size, void* d_ws, size_t ws_size,
                              hipStream_t stream) {
  const float* x    = (const float*)d_in[0];
  const float* wq   = (const float*)d_in[1];
  const float* bq   = (const float*)d_in[2];
  const float* wk   = (const float*)d_in[3];
  const float* bk   = (const float*)d_in[4];
  const float* wv   = (const float*)d_in[5];
  const float* bv   = (const float*)d_in[6];
  const float* gq   = (const float*)d_in[7];
  const float* gk   = (const float*)d_in[8];
  const float* wmix = (const float*)d_in[9];
  const float* wo   = (const float*)d_in[10];
  const float* bo   = (const float*)d_in[11];

  const int M = 4096;      // B*L
  const int K = 2048;      // QUERY_DIM
  const size_t MB = 1024 * 1024;

  char* ws = (char*)d_ws;
  // workspace (112 MB):
  unsigned short* xb    = (unsigned short*)(ws + 0 * MB);    // 16MB; dead after QKV gemm
  unsigned short* wqkvb = (unsigned short*)(ws + 16 * MB);   // 24MB; dead after QKV gemm
  unsigned short* AOb   = (unsigned short*)(ws + 16 * MB);   // 16MB alias (attn out)
  float*          invQ  = (float*)(ws + 33 * MB);            // 16KB alias (in dead wqkvb)
  float*          invK  = (float*)(ws + 33 * MB + 16384);    // 16KB
  unsigned short* Qb    = (unsigned short*)(ws + 40 * MB);   // 16MB (biased, pre-norm)
  unsigned short* Kb    = (unsigned short*)(ws + 56 * MB);   // 16MB (biased, pre-norm)
  unsigned short* Vt    = (unsigned short*)(ws + 72 * MB);   // 16MB (transposed V)
  unsigned short* wob   = (unsigned short*)(ws + 104 * MB);  // 8MB

  // all five casts in one kernel (25.2M elems, 4/thread)
  cast_main<<<24576, 256, 0, stream>>>(x, wq, wk, wv, wo, xb, wqkvb, wob);

  // fused QKV GEMM: 128x128 tiles, grid 48 x 32 (measured-best structure)
  gemm_bt<1><<<dim3(48, 32), 256, 0, stream>>>(xb, wqkvb, bq, bk, bv, Qb, Kb, Vt, K);

  // per-row inverse RMS norms (L2-hot reads of Qb/Kb)
  row_norms<<<dim3(M, 2), 256, 0, stream>>>(Qb, Kb, invQ, invK);

  // norm-folded attention
  attention_k<<<512, 512, 0, stream>>>(Qb, Kb, Vt, invQ, invK, gq, gk, wmix, AOb);

  // out-proj: 128x128 tiles, grid 16 x 32
  gemm_bt<0><<<dim3(16, 32), 256, 0, stream>>>(AOb, wob, bo, nullptr, nullptr, d_out, nullptr, nullptr, K);
}

// Round 16
// 214.973 us; speedup vs baseline: 1.0332x; 1.0028x over previous
//
#include <hip/hip_runtime.h>
#include <hip/hip_bf16.h>
#include <stdint.h>

typedef __attribute__((ext_vector_type(8))) short v8s;
typedef __attribute__((ext_vector_type(8))) __bf16 bf16x8;
typedef __attribute__((ext_vector_type(4))) float v4f;

__device__ __forceinline__ unsigned short f2bf(float f) {
  unsigned int u = __float_as_uint(f);
  u += 0x7fff + ((u >> 16) & 1);
  return (unsigned short)(u >> 16);
}
__device__ __forceinline__ float bf2f(unsigned short h) {
  return __uint_as_float(((unsigned int)h) << 16);
}

__device__ __forceinline__ void gload_lds16(const void* g, void* l) {
  __builtin_amdgcn_global_load_lds(
      (const __attribute__((address_space(1))) void*)g,
      (__attribute__((address_space(3))) void*)l,
      16, 0, 0);
}

// ---------------- merged cast f32 -> bf16 (x, wq, wk, wv, wo) ----------------
__global__ void cast_main(const float* __restrict__ x,  const float* __restrict__ wq,
                          const float* __restrict__ wk, const float* __restrict__ wv,
                          const float* __restrict__ wo,
                          unsigned short* __restrict__ xb, unsigned short* __restrict__ wqkvb,
                          unsigned short* __restrict__ wob) {
  const size_t MK = 8388608, NK = 4194304;  // 4096*2048, 2048*2048
  size_t i = ((size_t)blockIdx.x * 256 + threadIdx.x) * 4;
  const float* s; unsigned short* d; size_t off;
  if (i < MK)               { s = x;  d = xb;              off = i; }
  else if (i < MK + NK)     { s = wq; d = wqkvb;           off = i - MK; }
  else if (i < MK + 2 * NK) { s = wk; d = wqkvb + NK;      off = i - MK - NK; }
  else if (i < MK + 3 * NK) { s = wv; d = wqkvb + 2 * NK;  off = i - MK - 2 * NK; }
  else                      { s = wo; d = wob;             off = i - MK - 3 * NK; }
  float4 v = *(const float4*)(s + off);
  ushort4 o;
  o.x = f2bf(v.x); o.y = f2bf(v.y); o.z = f2bf(v.z); o.w = f2bf(v.w);
  *(ushort4*)(d + off) = o;
}

// ---------------- GEMM (m97 structure, 128x128, BK=64): C = A*B^T + bias ----
#define BM 128
#define BN 128
#define BK 64

template <int OUT>
__global__ __launch_bounds__(256, 2) void gemm_bt(
    const unsigned short* __restrict__ A,  // M x K bf16
    const unsigned short* __restrict__ B,  // Nfused x K bf16
    const float* __restrict__ bias0,
    const float* __restrict__ bias1,
    const float* __restrict__ bias2,
    void* __restrict__ D0, void* __restrict__ D1, void* __restrict__ D2,
    int K)
{
  __shared__ __align__(16) unsigned short Sh[2 * BM * BK];  // As | Bs, reused by epilogue
  unsigned short* As = Sh;
  unsigned short* Bs = Sh + BM * BK;

  const int tid  = threadIdx.x;
  const int lane = tid & 63;
  const int wid  = tid >> 6;            // 0..3
  const int wr   = wid >> 1, wc = wid & 1;

  const int tm = blockIdx.y * BM;
  const int tn = blockIdx.x * BN;

  const int srow = lane >> 3;
  const int scb  = lane & 7;
  const int gco  = (scb ^ srow) * 8;

  v4f acc[4][4];
#pragma unroll
  for (int m = 0; m < 4; ++m)
#pragma unroll
    for (int n = 0; n < 4; ++n)
      acc[m][n] = (v4f){0.f, 0.f, 0.f, 0.f};

  const unsigned short* Ab = A + (size_t)tm * K;
  const unsigned short* Bb = B + (size_t)tn * K;
  const int kTiles = K / BK;

  for (int kt = 0; kt < kTiles; ++kt) {
    const int k0 = kt * BK;
#pragma unroll
    for (int i = 0; i < 4; ++i) {
      const int r0 = wid * 32 + i * 8;
      gload_lds16(Ab + (size_t)(r0 + srow) * K + k0 + gco, &As[r0 * BK]);
    }
#pragma unroll
    for (int i = 0; i < 4; ++i) {
      const int r0 = wid * 32 + i * 8;
      gload_lds16(Bb + (size_t)(r0 + srow) * K + k0 + gco, &Bs[r0 * BK]);
    }
    __syncthreads();

#pragma unroll
    for (int ks = 0; ks < 2; ++ks) {
      bf16x8 av[4], bv[4];
#pragma unroll
      for (int m = 0; m < 4; ++m) {
        const int row  = wr * 64 + m * 16 + (lane & 15);
        const int cl   = ks * 4 + (lane >> 4);
        av[m] = *(const bf16x8*)&As[row * BK + ((cl ^ (row & 7)) * 8)];
      }
#pragma unroll
      for (int n = 0; n < 4; ++n) {
        const int row  = wc * 64 + n * 16 + (lane & 15);
        const int cl   = ks * 4 + (lane >> 4);
        bv[n] = *(const bf16x8*)&Bs[row * BK + ((cl ^ (row & 7)) * 8)];
      }
#pragma unroll
      for (int m = 0; m < 4; ++m)
#pragma unroll
        for (int n = 0; n < 4; ++n)
          acc[m][n] = __builtin_amdgcn_mfma_f32_16x16x32_bf16(av[m], bv[n], acc[m][n], 0, 0, 0);
    }
    __syncthreads();
  }

  const int cr0 = tm + wr * 64 + (lane >> 4) * 4;
  const int cc0 = tn + wc * 64 + (lane & 15);

  if (OUT == 0) {
    float* Dp = (float*)D0;
#pragma unroll
    for (int n = 0; n < 4; ++n) {
      const int col = cc0 + n * 16;
      const float bz = bias0[col];
#pragma unroll
      for (int m = 0; m < 4; ++m) {
#pragma unroll
        for (int r = 0; r < 4; ++r) {
          const int rr = cr0 + m * 16 + r;
          Dp[(size_t)rr * 2048 + col] = acc[m][n][r] + bz;
        }
      }
    }
  } else {
    const int sid = tn >> 11;
    const float* bp = (sid == 0) ? bias0 : (sid == 1) ? bias1 : bias2;
    unsigned short* Dq = (unsigned short*)((sid == 0) ? D0 : (sid == 1) ? D1 : D2);

    // stage 128x128 tile (+bias) into LDS (32KB exactly)
    const int rl0 = wr * 64 + (lane >> 4) * 4;   // local row base
    const int clb = wc * 64 + (lane & 15);       // local col base
#pragma unroll
    for (int n = 0; n < 4; ++n) {
      const int cl = clb + n * 16;               // local col 0..127
      const float bz = bp[(tn & 2047) + cl];     // tn is multiple of 128
#pragma unroll
      for (int m = 0; m < 4; ++m) {
#pragma unroll
        for (int r = 0; r < 4; ++r) {
          Sh[(rl0 + m * 16 + r) * 128 + cl] = f2bf(acc[m][n][r] + bz);
        }
      }
    }
    __syncthreads();

    if (sid < 2) {
      const int tn2 = tn & 2047;
#pragma unroll
      for (int it = 0; it < 8; ++it) {           // 8 * 256 * 8 = 16384 elems
        const int off = (it * 256 + tid) * 8;
        const int row = off >> 7, col = off & 127;
        *(v8s*)(Dq + (size_t)(tm + row) * 2048 + tn2 + col) = *(const v8s*)&Sh[off];
      }
    } else {
      const int bb = tm >> 11, ll0 = tm & 2047;
      const int hh = (tn & 2047) >> 7;
      unsigned short* dst = Dq + (((size_t)(bb * 16 + hh)) * 2048 + ll0) * 128;
#pragma unroll
      for (int it = 0; it < 8; ++it) {
        const int off = (it * 256 + tid) * 8;
        *(v8s*)(dst + off) = *(const v8s*)&Sh[off];
      }
    }
  }
}

// ---------------- per-row inverse RMS norms for Q and K ----------------------
__global__ __launch_bounds__(256) void row_norms(
    const unsigned short* __restrict__ Qb, const unsigned short* __restrict__ Kb,
    float* __restrict__ invQ, float* __restrict__ invK)
{
  const int row = blockIdx.x;            // 0..4095 (b*L + l)
  const bool isQ = (blockIdx.y == 0);
  const unsigned short* src = (isQ ? Qb : Kb) + (size_t)row * 2048;
  __shared__ float red[4];

  const int t = threadIdx.x;
  v8s raw = *(const v8s*)(src + t * 8);
  float ss = 0.f;
#pragma unroll
  for (int j = 0; j < 8; ++j) { float x = bf2f((unsigned short)raw[j]); ss += x * x; }
#pragma unroll
  for (int o = 32; o > 0; o >>= 1) ss += __shfl_xor(ss, o, 64);
  if ((t & 63) == 0) red[t >> 6] = ss;
  __syncthreads();
  if (t == 0) {
    const float tot = red[0] + red[1] + red[2] + red[3];
    (isQ ? invQ : invK)[row] = rsqrtf(tot * (1.0f / 2048.0f) + 1e-6f);
  }
}

// ---------------- attention: norm-folded, time-shared K/V LDS buffer ---------
// One 64KB buffer: stage K -> pass 1 -> barrier -> stage V into SAME buffer
// (K reads complete; V fetch hides under softmax) -> vmcnt(0)+barrier -> pass 2.
// LDS 73.5KB + VGPR cap 128 (needs ~100) -> 2 blocks/CU, no spill.
__global__ __launch_bounds__(512, 2) void attention_k(
    const unsigned short* __restrict__ Qb,
    const unsigned short* __restrict__ Kb,
    const unsigned short* __restrict__ Vt,
    const float* __restrict__ invQ, const float* __restrict__ invK,
    const float* __restrict__ gq, const float* __restrict__ gk,
    const float* __restrict__ wmix,
    unsigned short* __restrict__ AO)
{
  const int bid   = blockIdx.x;          // ch*32 + plane
  const int plane = bid & 31;
  const int ch    = bid >> 5;            // 0..15
  const int b = plane >> 4, h = plane & 15;
  const int l0 = ch * 128;
  const int w0 = (l0 + 2048 - 64) & 2047;   // staged window start

  __shared__ __align__(16) unsigned short KVs[256 * 128];  // 64KB, K then V
  __shared__ float sc[128][17];

  const int t    = threadIdx.x;
  const int lane = t & 63;
  const int w    = t >> 6;               // wave 0..7
  const int li   = t >> 2;               // 0..127
  const int q    = t & 3;                // 32-elem d quarter
  const int myl  = l0 + li;
  const int grow = b * 2048 + myl;

  const size_t pbase = (size_t)plane * (2048 * 128);

  const int lr4 = lane >> 4;             // row within 4-row segment
  const int cp  = lane & 15;             // phys chunk this lane fills

  // ---- stage 256-row K window (from row-major Kb) ----
#pragma unroll
  for (int j = 0; j < 8; ++j) {
    const int seg = w * 8 + j;           // 0..63
    const int rl  = seg * 4 + lr4;       // local row 0..255
    const int cl  = cp ^ (rl & 7);       // logical chunk to fetch
    const int g   = (w0 + rl) & 2047;
    gload_lds16(Kb + ((size_t)(b * 2048 + g)) * 2048 + h * 128 + cl * 8, &KVs[seg * 512]);
  }

  // ---- Q: load raw, normalize, mix, fold gk (overlaps staging latency) ----
  float qg[32];
  {
    float qn[32];
    const unsigned short* qp = Qb + (size_t)grow * 2048 + h * 128 + q * 32;
    const float iq = invQ[grow];
    const float* gqp = gq + h * 128 + q * 32;
#pragma unroll
    for (int i = 0; i < 4; ++i) {
      v8s qv = *(const v8s*)(qp + i * 8);
#pragma unroll
      for (int j = 0; j < 8; ++j)
        qn[i * 8 + j] = bf2f((unsigned short)qv[j]) * iq * gqp[i * 8 + j];
    }
    // neighbor's top 8 (circular within the 128-dim head): lane of quarter q-1
    float prev[8];
    const int nb = (t & ~3) | ((q + 3) & 3);
#pragma unroll
    for (int j = 0; j < 8; ++j) prev[j] = __shfl(qn[24 + j], nb & 63, 64);
    const float scale = 0.08838834764831845f;  // 1/sqrt(128)
    const float w0m = wmix[0] * scale, w1m = wmix[1] * scale, w2m = wmix[2] * scale;
    const float w3m = wmix[3] * scale, w4m = wmix[4] * scale;
    const float* gkp = gk + h * 128 + q * 32;
#pragma unroll
    for (int i = 0; i < 32; ++i) {
      const float s1 = (i >= 1) ? qn[i - 1] : prev[7 + i];
      const float s2 = (i >= 2) ? qn[i - 2] : prev[6 + i];
      const float s4 = (i >= 4) ? qn[i - 4] : prev[4 + i];
      const float s8 = (i >= 8) ? qn[i - 8] : prev[i];
      qg[i] = (w0m * qn[i] + w1m * s1 + w2m * s2 + w3m * s4 + w4m * s8) * gkp[i];
    }
  }

  asm volatile("s_waitcnt vmcnt(0)" ::: "memory");
  __syncthreads();

  const int SH[16] = {0, 1, -1, 3, -3, 7, -7, 20, -20, 53, -53, 141, -141, 380, -380, 1024};

  // pass 1: scores (score = (qg . k_raw) * invK[row])
#pragma unroll
  for (int s = 0; s < 16; ++s) {
    const int row = (myl - SH[s]) & 2047;
    float dot = 0.f;
    if (s < 11) {
      const int rl = li + 64 - SH[s];    // in [11, 244]
#pragma unroll
      for (int i = 0; i < 4; ++i) {
        v8s kv = *(const v8s*)&KVs[rl * 128 + (((q * 4 + i) ^ (rl & 7)) * 8)];
#pragma unroll
        for (int j = 0; j < 8; ++j) dot += qg[i * 8 + j] * bf2f((unsigned short)kv[j]);
      }
    } else {
      const unsigned short* kp = Kb + ((size_t)(b * 2048 + row)) * 2048 + h * 128 + q * 32;
#pragma unroll
      for (int i = 0; i < 4; ++i) {
        v8s kv = *(const v8s*)(kp + i * 8);
#pragma unroll
        for (int j = 0; j < 8; ++j) dot += qg[i * 8 + j] * bf2f((unsigned short)kv[j]);
      }
    }
    dot += __shfl_xor(dot, 1, 64);
    dot += __shfl_xor(dot, 2, 64);
    if (q == 0) sc[li][s] = dot * invK[b * 2048 + row];
  }
  __syncthreads();   // all K reads from KVs + score writes complete

  // ---- stage V window into the same buffer (latency hides under softmax) ----
#pragma unroll
  for (int j = 0; j < 8; ++j) {
    const int seg = w * 8 + j;
    const int rl  = seg * 4 + lr4;
    const int cl  = cp ^ (rl & 7);
    const int g   = (w0 + rl) & 2047;
    gload_lds16(Vt + pbase + (size_t)g * 128 + cl * 8, &KVs[seg * 512]);
  }

  // softmax over 16 shifts (sc only; no KVs access)
  {
    float v0[16];
#pragma unroll
    for (int s = 0; s < 16; ++s) v0[s] = sc[li][s];
    float mx = v0[0];
#pragma unroll
    for (int s = 1; s < 16; ++s) mx = fmaxf(mx, v0[s]);
    float sum = 0.f;
    float e[4];
#pragma unroll
    for (int s = 0; s < 16; ++s) {
      const float ee = __expf(v0[s] - mx);
      sum += ee;
      if ((s >> 2) == q) e[s & 3] = ee;
    }
    const float inv = 1.f / sum;
    __syncthreads();
#pragma unroll
    for (int i = 0; i < 4; ++i) sc[li][q * 4 + i] = e[i] * inv;
  }
  asm volatile("s_waitcnt vmcnt(0)" ::: "memory");  // own V stage landed
  __syncthreads();                                   // all waves' V + prob writes

  // pass 2: output accumulate (V from KVs)
  float o[32];
#pragma unroll
  for (int i = 0; i < 32; ++i) o[i] = 0.f;
#pragma unroll
  for (int s = 0; s < 16; ++s) {
    const float p = sc[li][s];
    if (s < 11) {
      const int rl = li + 64 - SH[s];
#pragma unroll
      for (int i = 0; i < 4; ++i) {
        v8s vv = *(const v8s*)&KVs[rl * 128 + (((q * 4 + i) ^ (rl & 7)) * 8)];
#pragma unroll
        for (int j = 0; j < 8; ++j) o[i * 8 + j] += p * bf2f((unsigned short)vv[j]);
      }
    } else {
      const int row = (myl - SH[s]) & 2047;
      const unsigned short* vp = Vt + pbase + (size_t)row * 128 + q * 32;
#pragma unroll
      for (int i = 0; i < 4; ++i) {
        v8s vv = *(const v8s*)(vp + i * 8);
#pragma unroll
        for (int j = 0; j < 8; ++j) o[i * 8 + j] += p * bf2f((unsigned short)vv[j]);
      }
    }
  }

  unsigned short* op = AO + ((size_t)grow) * 2048 + h * 128 + q * 32;
#pragma unroll
  for (int i = 0; i < 4; ++i) {
    v8s ov;
#pragma unroll
    for (int j = 0; j < 8; ++j) ov[j] = (short)f2bf(o[i * 8 + j]);
    *(v8s*)(op + i * 8) = ov;
  }
}

// ---------------- launch ----------------
extern "C" void kernel_launch(void* const* d_in, const int* in_sizes, int n_in,
                              void* d_out, int out_size, void* d_ws, size_t ws_size,
                              hipStream_t stream) {
  const float* x    = (const float*)d_in[0];
  const float* wq   = (const float*)d_in[1];
  const float* bq   = (const float*)d_in[2];
  const float* wk   = (const float*)d_in[3];
  const float* bk   = (const float*)d_in[4];
  const float* wv   = (const float*)d_in[5];
  const float* bv   = (const float*)d_in[6];
  const float* gq   = (const float*)d_in[7];
  const float* gk   = (const float*)d_in[8];
  const float* wmix = (const float*)d_in[9];
  const float* wo   = (const float*)d_in[10];
  const float* bo   = (const float*)d_in[11];

  const int M = 4096;      // B*L
  const int K = 2048;      // QUERY_DIM
  const size_t MB = 1024 * 1024;

  char* ws = (char*)d_ws;
  // workspace (112 MB):
  unsigned short* xb    = (unsigned short*)(ws + 0 * MB);    // 16MB; dead after QKV gemm
  unsigned short* wqkvb = (unsigned short*)(ws + 16 * MB);   // 24MB; dead after QKV gemm
  unsigned short* AOb   = (unsigned short*)(ws + 16 * MB);   // 16MB alias (attn out)
  float*          invQ  = (float*)(ws + 33 * MB);            // 16KB alias (in dead wqkvb)
  float*          invK  = (float*)(ws + 33 * MB + 16384);    // 16KB
  unsigned short* Qb    = (unsigned short*)(ws + 40 * MB);   // 16MB (biased, pre-norm)
  unsigned short* Kb    = (unsigned short*)(ws + 56 * MB);   // 16MB (biased, pre-norm)
  unsigned short* Vt    = (unsigned short*)(ws + 72 * MB);   // 16MB (transposed V)
  unsigned short* wob   = (unsigned short*)(ws + 104 * MB);  // 8MB

  // all five casts in one kernel (25.2M elems, 4/thread)
  cast_main<<<24576, 256, 0, stream>>>(x, wq, wk, wv, wo, xb, wqkvb, wob);

  // fused QKV GEMM: 128x128 tiles, grid 48 x 32 (measured-best structure)
  gemm_bt<1><<<dim3(48, 32), 256, 0, stream>>>(xb, wqkvb, bq, bk, bv, Qb, Kb, Vt, K);

  // per-row inverse RMS norms (L2-hot reads of Qb/Kb)
  row_norms<<<dim3(M, 2), 256, 0, stream>>>(Qb, Kb, invQ, invK);

  // norm-folded attention (time-shared K/V buffer, 2 blocks/CU)
  attention_k<<<512, 512, 0, stream>>>(Qb, Kb, Vt, invQ, invK, gq, gk, wmix, AOb);

  // out-proj: 128x128 tiles, grid 16 x 32
  gemm_bt<0><<<dim3(16, 32), 256, 0, stream>>>(AOb, wob, bo, nullptr, nullptr, d_out, nullptr, nullptr, K);
}

// Round 19
// 211.282 us; speedup vs baseline: 1.0513x; 1.0175x over previous
//
#include <hip/hip_runtime.h>
#include <hip/hip_bf16.h>
#include <stdint.h>

typedef __attribute__((ext_vector_type(8))) short v8s;
typedef __attribute__((ext_vector_type(8))) __bf16 bf16x8;
typedef __attribute__((ext_vector_type(4))) float v4f;

__device__ __forceinline__ unsigned short f2bf(float f) {
  unsigned int u = __float_as_uint(f);
  u += 0x7fff + ((u >> 16) & 1);
  return (unsigned short)(u >> 16);
}
__device__ __forceinline__ float bf2f(unsigned short h) {
  return __uint_as_float(((unsigned int)h) << 16);
}

__device__ __forceinline__ void gload_lds16(const void* g, void* l) {
  __builtin_amdgcn_global_load_lds(
      (const __attribute__((address_space(1))) void*)g,
      (__attribute__((address_space(3))) void*)l,
      16, 0, 0);
}

// ------- merged cast f32 -> bf16 (x, wq, wk, wv, wo) + zero sqQ/sqK ---------
__global__ void cast_main(const float* __restrict__ x,  const float* __restrict__ wq,
                          const float* __restrict__ wk, const float* __restrict__ wv,
                          const float* __restrict__ wo,
                          unsigned short* __restrict__ xb, unsigned short* __restrict__ wqkvb,
                          unsigned short* __restrict__ wob,
                          float* __restrict__ sqQ, float* __restrict__ sqK) {
  const size_t MK = 8388608, NK = 4194304;  // 4096*2048, 2048*2048
  const size_t gid = (size_t)blockIdx.x * 256 + threadIdx.x;
  if (gid < 4096) { sqQ[gid] = 0.f; sqK[gid] = 0.f; }
  size_t i = gid * 4;
  const float* s; unsigned short* d; size_t off;
  if (i < MK)               { s = x;  d = xb;              off = i; }
  else if (i < MK + NK)     { s = wq; d = wqkvb;           off = i - MK; }
  else if (i < MK + 2 * NK) { s = wk; d = wqkvb + NK;      off = i - MK - NK; }
  else if (i < MK + 3 * NK) { s = wv; d = wqkvb + 2 * NK;  off = i - MK - 2 * NK; }
  else                      { s = wo; d = wob;             off = i - MK - 3 * NK; }
  float4 v = *(const float4*)(s + off);
  ushort4 o;
  o.x = f2bf(v.x); o.y = f2bf(v.y); o.z = f2bf(v.z); o.w = f2bf(v.w);
  *(ushort4*)(d + off) = o;
}

// ---------------- GEMM (m97 structure, 128x128, BK=64): C = A*B^T + bias ----
// OUT=0: f32 row-major. OUT=1: fused QKV epilogue; Q/K also accumulate
// per-row sum-of-squares into sqQ/sqK (atomicAdd; zeroed by cast_main).
#define BM 128
#define BN 128
#define BK 64

template <int OUT>
__global__ __launch_bounds__(256, 2) void gemm_bt(
    const unsigned short* __restrict__ A,  // M x K bf16
    const unsigned short* __restrict__ B,  // Nfused x K bf16
    const float* __restrict__ bias0,
    const float* __restrict__ bias1,
    const float* __restrict__ bias2,
    void* __restrict__ D0, void* __restrict__ D1, void* __restrict__ D2,
    float* __restrict__ sqQ, float* __restrict__ sqK,
    int K)
{
  __shared__ __align__(16) unsigned short Sh[2 * BM * BK];  // As | Bs, reused by epilogue
  unsigned short* As = Sh;
  unsigned short* Bs = Sh + BM * BK;

  const int tid  = threadIdx.x;
  const int lane = tid & 63;
  const int wid  = tid >> 6;            // 0..3
  const int wr   = wid >> 1, wc = wid & 1;

  const int tm = blockIdx.y * BM;
  const int tn = blockIdx.x * BN;

  const int srow = lane >> 3;
  const int scb  = lane & 7;
  const int gco  = (scb ^ srow) * 8;

  v4f acc[4][4];
#pragma unroll
  for (int m = 0; m < 4; ++m)
#pragma unroll
    for (int n = 0; n < 4; ++n)
      acc[m][n] = (v4f){0.f, 0.f, 0.f, 0.f};

  const unsigned short* Ab = A + (size_t)tm * K;
  const unsigned short* Bb = B + (size_t)tn * K;
  const int kTiles = K / BK;

  for (int kt = 0; kt < kTiles; ++kt) {
    const int k0 = kt * BK;
#pragma unroll
    for (int i = 0; i < 4; ++i) {
      const int r0 = wid * 32 + i * 8;
      gload_lds16(Ab + (size_t)(r0 + srow) * K + k0 + gco, &As[r0 * BK]);
    }
#pragma unroll
    for (int i = 0; i < 4; ++i) {
      const int r0 = wid * 32 + i * 8;
      gload_lds16(Bb + (size_t)(r0 + srow) * K + k0 + gco, &Bs[r0 * BK]);
    }
    __syncthreads();

#pragma unroll
    for (int ks = 0; ks < 2; ++ks) {
      bf16x8 av[4], bv[4];
#pragma unroll
      for (int m = 0; m < 4; ++m) {
        const int row  = wr * 64 + m * 16 + (lane & 15);
        const int cl   = ks * 4 + (lane >> 4);
        av[m] = *(const bf16x8*)&As[row * BK + ((cl ^ (row & 7)) * 8)];
      }
#pragma unroll
      for (int n = 0; n < 4; ++n) {
        const int row  = wc * 64 + n * 16 + (lane & 15);
        const int cl   = ks * 4 + (lane >> 4);
        bv[n] = *(const bf16x8*)&Bs[row * BK + ((cl ^ (row & 7)) * 8)];
      }
#pragma unroll
      for (int m = 0; m < 4; ++m)
#pragma unroll
        for (int n = 0; n < 4; ++n)
          acc[m][n] = __builtin_amdgcn_mfma_f32_16x16x32_bf16(av[m], bv[n], acc[m][n], 0, 0, 0);
    }
    __syncthreads();
  }

  const int cr0 = tm + wr * 64 + (lane >> 4) * 4;
  const int cc0 = tn + wc * 64 + (lane & 15);

  if (OUT == 0) {
    float* Dp = (float*)D0;
#pragma unroll
    for (int n = 0; n < 4; ++n) {
      const int col = cc0 + n * 16;
      const float bz = bias0[col];
#pragma unroll
      for (int m = 0; m < 4; ++m) {
#pragma unroll
        for (int r = 0; r < 4; ++r) {
          const int rr = cr0 + m * 16 + r;
          Dp[(size_t)rr * 2048 + col] = acc[m][n][r] + bz;
        }
      }
    }
  } else {
    const int sid = tn >> 11;
    const float* bp = (sid == 0) ? bias0 : (sid == 1) ? bias1 : bias2;
    unsigned short* Dq = (unsigned short*)((sid == 0) ? D0 : (sid == 1) ? D1 : D2);

    // stage 128x128 tile (+bias) into LDS (32KB exactly)
    const int rl0 = wr * 64 + (lane >> 4) * 4;   // local row base
    const int clb = wc * 64 + (lane & 15);       // local col base
#pragma unroll
    for (int n = 0; n < 4; ++n) {
      const int cl = clb + n * 16;               // local col 0..127
      const float bz = bp[(tn & 2047) + cl];     // tn is multiple of 128
#pragma unroll
      for (int m = 0; m < 4; ++m) {
#pragma unroll
        for (int r = 0; r < 4; ++r) {
          Sh[(rl0 + m * 16 + r) * 128 + cl] = f2bf(acc[m][n][r] + bz);
        }
      }
    }
    __syncthreads();

    if (sid < 2) {
      // per-row sum of squares (2 threads/row, 64 elems each) -> atomicAdd
      {
        const int row = tid >> 1;
        const int half = tid & 1;
        float ssum = 0.f;
#pragma unroll
        for (int i = 0; i < 8; ++i) {
          v8s vv = *(const v8s*)&Sh[row * 128 + half * 64 + i * 8];
#pragma unroll
          for (int j = 0; j < 8; ++j) {
            const float xv = bf2f((unsigned short)vv[j]);
            ssum += xv * xv;
          }
        }
        ssum += __shfl_xor(ssum, 1, 64);
        if (half == 0) atomicAdd(&((sid == 0) ? sqQ : sqK)[tm + row], ssum);
      }
      const int tn2 = tn & 2047;
#pragma unroll
      for (int it = 0; it < 8; ++it) {           // 8 * 256 * 8 = 16384 elems
        const int off = (it * 256 + tid) * 8;
        const int row = off >> 7, col = off & 127;
        *(v8s*)(Dq + (size_t)(tm + row) * 2048 + tn2 + col) = *(const v8s*)&Sh[off];
      }
    } else {
      const int bb = tm >> 11, ll0 = tm & 2047;
      const int hh = (tn & 2047) >> 7;
      unsigned short* dst = Dq + (((size_t)(bb * 16 + hh)) * 2048 + ll0) * 128;
#pragma unroll
      for (int it = 0; it < 8; ++it) {
        const int off = (it * 256 + tid) * 8;
        *(v8s*)(dst + off) = *(const v8s*)&Sh[off];
      }
    }
  }
}

// ---------------- attention: norm-folded, time-shared K/V LDS buffer ---------
// rsqrt computed inline from sqQ/sqK (sum of squares accumulated by QKV gemm).
__global__ __launch_bounds__(512, 2) void attention_k(
    const unsigned short* __restrict__ Qb,
    const unsigned short* __restrict__ Kb,
    const unsigned short* __restrict__ Vt,
    const float* __restrict__ sqQ, const float* __restrict__ sqK,
    const float* __restrict__ gq, const float* __restrict__ gk,
    const float* __restrict__ wmix,
    unsigned short* __restrict__ AO)
{
  const int bid   = blockIdx.x;          // ch*32 + plane
  const int plane = bid & 31;
  const int ch    = bid >> 5;            // 0..15
  const int b = plane >> 4, h = plane & 15;
  const int l0 = ch * 128;
  const int w0 = (l0 + 2048 - 64) & 2047;   // staged window start

  __shared__ __align__(16) unsigned short KVs[256 * 128];  // 64KB, K then V
  __shared__ float sc[128][17];

  const int t    = threadIdx.x;
  const int lane = t & 63;
  const int w    = t >> 6;               // wave 0..7
  const int li   = t >> 2;               // 0..127
  const int q    = t & 3;                // 32-elem d quarter
  const int myl  = l0 + li;
  const int grow = b * 2048 + myl;

  const size_t pbase = (size_t)plane * (2048 * 128);

  const int lr4 = lane >> 4;             // row within 4-row segment
  const int cp  = lane & 15;             // phys chunk this lane fills

  // ---- stage 256-row K window (from row-major Kb) ----
#pragma unroll
  for (int j = 0; j < 8; ++j) {
    const int seg = w * 8 + j;           // 0..63
    const int rl  = seg * 4 + lr4;       // local row 0..255
    const int cl  = cp ^ (rl & 7);       // logical chunk to fetch
    const int g   = (w0 + rl) & 2047;
    gload_lds16(Kb + ((size_t)(b * 2048 + g)) * 2048 + h * 128 + cl * 8, &KVs[seg * 512]);
  }

  // ---- Q: load raw, normalize, mix, fold gk (overlaps staging latency) ----
  float qg[32];
  {
    float qn[32];
    const unsigned short* qp = Qb + (size_t)grow * 2048 + h * 128 + q * 32;
    const float iq = rsqrtf(sqQ[grow] * (1.0f / 2048.0f) + 1e-6f);
    const float* gqp = gq + h * 128 + q * 32;
#pragma unroll
    for (int i = 0; i < 4; ++i) {
      v8s qv = *(const v8s*)(qp + i * 8);
#pragma unroll
      for (int j = 0; j < 8; ++j)
        qn[i * 8 + j] = bf2f((unsigned short)qv[j]) * iq * gqp[i * 8 + j];
    }
    // neighbor's top 8 (circular within the 128-dim head): lane of quarter q-1
    float prev[8];
    const int nb = (t & ~3) | ((q + 3) & 3);
#pragma unroll
    for (int j = 0; j < 8; ++j) prev[j] = __shfl(qn[24 + j], nb & 63, 64);
    const float scale = 0.08838834764831845f;  // 1/sqrt(128)
    const float w0m = wmix[0] * scale, w1m = wmix[1] * scale, w2m = wmix[2] * scale;
    const float w3m = wmix[3] * scale, w4m = wmix[4] * scale;
    const float* gkp = gk + h * 128 + q * 32;
#pragma unroll
    for (int i = 0; i < 32; ++i) {
      const float s1 = (i >= 1) ? qn[i - 1] : prev[7 + i];
      const float s2 = (i >= 2) ? qn[i - 2] : prev[6 + i];
      const float s4 = (i >= 4) ? qn[i - 4] : prev[4 + i];
      const float s8 = (i >= 8) ? qn[i - 8] : prev[i];
      qg[i] = (w0m * qn[i] + w1m * s1 + w2m * s2 + w3m * s4 + w4m * s8) * gkp[i];
    }
  }

  asm volatile("s_waitcnt vmcnt(0)" ::: "memory");
  __syncthreads();

  const int SH[16] = {0, 1, -1, 3, -3, 7, -7, 20, -20, 53, -53, 141, -141, 380, -380, 1024};

  // pass 1: scores (score = (qg . k_raw) * invK[row])
#pragma unroll
  for (int s = 0; s < 16; ++s) {
    const int row = (myl - SH[s]) & 2047;
    float dot = 0.f;
    if (s < 11) {
      const int rl = li + 64 - SH[s];    // in [11, 244]
#pragma unroll
      for (int i = 0; i < 4; ++i) {
        v8s kv = *(const v8s*)&KVs[rl * 128 + (((q * 4 + i) ^ (rl & 7)) * 8)];
#pragma unroll
        for (int j = 0; j < 8; ++j) dot += qg[i * 8 + j] * bf2f((unsigned short)kv[j]);
      }
    } else {
      const unsigned short* kp = Kb + ((size_t)(b * 2048 + row)) * 2048 + h * 128 + q * 32;
#pragma unroll
      for (int i = 0; i < 4; ++i) {
        v8s kv = *(const v8s*)(kp + i * 8);
#pragma unroll
        for (int j = 0; j < 8; ++j) dot += qg[i * 8 + j] * bf2f((unsigned short)kv[j]);
      }
    }
    dot += __shfl_xor(dot, 1, 64);
    dot += __shfl_xor(dot, 2, 64);
    if (q == 0)
      sc[li][s] = dot * rsqrtf(sqK[b * 2048 + row] * (1.0f / 2048.0f) + 1e-6f);
  }
  __syncthreads();   // all K reads from KVs + score writes complete

  // ---- stage V window into the same buffer (latency hides under softmax) ----
#pragma unroll
  for (int j = 0; j < 8; ++j) {
    const int seg = w * 8 + j;
    const int rl  = seg * 4 + lr4;
    const int cl  = cp ^ (rl & 7);
    const int g   = (w0 + rl) & 2047;
    gload_lds16(Vt + pbase + (size_t)g * 128 + cl * 8, &KVs[seg * 512]);
  }

  // softmax over 16 shifts (sc only; no KVs access)
  {
    float v0[16];
#pragma unroll
    for (int s = 0; s < 16; ++s) v0[s] = sc[li][s];
    float mx = v0[0];
#pragma unroll
    for (int s = 1; s < 16; ++s) mx = fmaxf(mx, v0[s]);
    float sum = 0.f;
    float e[4];
#pragma unroll
    for (int s = 0; s < 16; ++s) {
      const float ee = __expf(v0[s] - mx);
      sum += ee;
      if ((s >> 2) == q) e[s & 3] = ee;
    }
    const float inv = 1.f / sum;
    __syncthreads();
#pragma unroll
    for (int i = 0; i < 4; ++i) sc[li][q * 4 + i] = e[i] * inv;
  }
  asm volatile("s_waitcnt vmcnt(0)" ::: "memory");  // own V stage landed
  __syncthreads();                                   // all waves' V + prob writes

  // pass 2: output accumulate (V from KVs)
  float o[32];
#pragma unroll
  for (int i = 0; i < 32; ++i) o[i] = 0.f;
#pragma unroll
  for (int s = 0; s < 16; ++s) {
    const float p = sc[li][s];
    if (s < 11) {
      const int rl = li + 64 - SH[s];
#pragma unroll
      for (int i = 0; i < 4; ++i) {
        v8s vv = *(const v8s*)&KVs[rl * 128 + (((q * 4 + i) ^ (rl & 7)) * 8)];
#pragma unroll
        for (int j = 0; j < 8; ++j) o[i * 8 + j] += p * bf2f((unsigned short)vv[j]);
      }
    } else {
      const int row = (myl - SH[s]) & 2047;
      const unsigned short* vp = Vt + pbase + (size_t)row * 128 + q * 32;
#pragma unroll
      for (int i = 0; i < 4; ++i) {
        v8s vv = *(const v8s*)(vp + i * 8);
#pragma unroll
        for (int j = 0; j < 8; ++j) o[i * 8 + j] += p * bf2f((unsigned short)vv[j]);
      }
    }
  }

  unsigned short* op = AO + ((size_t)grow) * 2048 + h * 128 + q * 32;
#pragma unroll
  for (int i = 0; i < 4; ++i) {
    v8s ov;
#pragma unroll
    for (int j = 0; j < 8; ++j) ov[j] = (short)f2bf(o[i * 8 + j]);
    *(v8s*)(op + i * 8) = ov;
  }
}

// ---------------- launch ----------------
extern "C" void kernel_launch(void* const* d_in, const int* in_sizes, int n_in,
                              void* d_out, int out_size, void* d_ws, size_t ws_size,
                              hipStream_t stream) {
  const float* x    = (const float*)d_in[0];
  const float* wq   = (const float*)d_in[1];
  const float* bq   = (const float*)d_in[2];
  const float* wk   = (const float*)d_in[3];
  const float* bk   = (const float*)d_in[4];
  const float* wv   = (const float*)d_in[5];
  const float* bv   = (const float*)d_in[6];
  const float* gq   = (const float*)d_in[7];
  const float* gk   = (const float*)d_in[8];
  const float* wmix = (const float*)d_in[9];
  const float* wo   = (const float*)d_in[10];
  const float* bo   = (const float*)d_in[11];

  const int K = 2048;      // QUERY_DIM
  const size_t MB = 1024 * 1024;

  char* ws = (char*)d_ws;
  // workspace (112 MB):
  unsigned short* xb    = (unsigned short*)(ws + 0 * MB);    // 16MB; dead after QKV gemm
  unsigned short* wqkvb = (unsigned short*)(ws + 16 * MB);   // 24MB; dead after QKV gemm
  unsigned short* AOb   = (unsigned short*)(ws + 16 * MB);   // 16MB alias (attn out)
  unsigned short* Qb    = (unsigned short*)(ws + 40 * MB);   // 16MB (biased, pre-norm)
  unsigned short* Kb    = (unsigned short*)(ws + 56 * MB);   // 16MB (biased, pre-norm)
  unsigned short* Vt    = (unsigned short*)(ws + 72 * MB);   // 16MB (transposed V)
  float*          sqQ   = (float*)(ws + 88 * MB);            // 16KB (free slot)
  float*          sqK   = (float*)(ws + 88 * MB + 16384);    // 16KB
  unsigned short* wob   = (unsigned short*)(ws + 104 * MB);  // 8MB

  // all five casts + sqQ/sqK zeroing in one kernel
  cast_main<<<24576, 256, 0, stream>>>(x, wq, wk, wv, wo, xb, wqkvb, wob, sqQ, sqK);

  // fused QKV GEMM (+ per-row sum-of-squares accumulation)
  gemm_bt<1><<<dim3(48, 32), 256, 0, stream>>>(xb, wqkvb, bq, bk, bv, Qb, Kb, Vt, sqQ, sqK, K);

  // norm-folded attention (rsqrt inline from sums)
  attention_k<<<512, 512, 0, stream>>>(Qb, Kb, Vt, sqQ, sqK, gq, gk, wmix, AOb);

  // out-proj: 11 args (sqQ/sqK unused in OUT=0 path)
  gemm_bt<0><<<dim3(16, 32), 256, 0, stream>>>(AOb, wob, bo, nullptr, nullptr,
                                               d_out, nullptr, nullptr,
                                               nullptr, nullptr, K);
}